// Round 1
// baseline (151.157 us; speedup 1.0000x reference)
//
#include <hip/hip_runtime.h>
#include <hip/hip_fp16.h>

// QLinear with per-k fp16 requantized accumulation (mptorch fma semantics).
// out = q16( q16_scan_fma( q8(x) @ q8(W)^T ) + q8(b) )
// v_pk_fma_f16 (single RNE rounding) == reference fp32-mul/add/quant chain.
//
// This version: LDS-issue-bound fix.
//  - x packed as {k0,k1} uints at transpose time; broadcast into pk_fma via
//    op_sel/op_sel_hi (free in-register splat, no pre-splatted LDS format).
//  - 8m x 4n register tile: per k-pair 2x ds_read_b128 (x, 2-addr broadcast)
//    + 2x ds_read_b64 (w, fusable read2) feed 32 pk_fma.
//  - global_load_lds(16B) double-buffered staging, 1 barrier per BK-chunk.
//  - bias quant fused into GEMM epilogue (one launch fewer).

#define M_DIM 2048
#define N_DIM 1024
#define K_DIM 1024

#define BM 32
#define BN 128
#define BK 64
#define NCHUNK (K_DIM / BK)

typedef unsigned u32;

// exact E4M3 (exp=4, man=3) quantization of an fp32 value, result fp32
__device__ __forceinline__ float quant_e4m3(float v) {
  unsigned au = __float_as_uint(v) & 0x7fffffffu;
  if (au == 0u) return v;                 // +-0
  int e = (int)(au >> 23) - 127;          // floor(log2|v|) for normals
  if (e < -6) e = -6;                     // fp32 subnorms hit the clamp too
  float s  = __uint_as_float((unsigned)(130 - e) << 23);  // 2^(3-e), exact
  float is = __uint_as_float((unsigned)(124 + e) << 23);  // 2^(e-3), exact
  float r = rintf(v * s) * is;            // RNE (half-to-even), all steps exact
  return fminf(240.f, fmaxf(-240.f, r));
}

// ---------- transpose + quant kernels ----------

// w path: in [R][C] fp32 -> out [C][R] fp16 (E4M3 values are fp16-exact)
__global__ __launch_bounds__(256) void qt_kernel(const float* __restrict__ in,
                                                 __half* __restrict__ outp,
                                                 int R, int C) {
  __shared__ float tile[32][33];
  const int tx = threadIdx.x & 31;
  const int ty = threadIdx.x >> 5;
  const int c0 = blockIdx.x * 32;
  const int r0 = blockIdx.y * 32;
#pragma unroll
  for (int i = 0; i < 4; i++) {
    int r = r0 + ty + i * 8;
    tile[ty + i * 8][tx] = quant_e4m3(in[(size_t)r * C + c0 + tx]);
  }
  __syncthreads();
#pragma unroll
  for (int i = 0; i < 4; i++) {
    int c = c0 + ty + i * 8;
    outp[(size_t)c * R + r0 + tx] = __float2half(tile[tx][ty + i * 8]);
  }
}

// x path: in [R][C] fp32 -> out [C/2][R] uints; uint = {q(in[r][2t]), q(in[r][2t+1])}
__global__ __launch_bounds__(256) void qt_pack_kernel(const float* __restrict__ in,
                                                      u32* __restrict__ outp,
                                                      int R, int C) {
  __shared__ float tile[32][33];
  const int tx = threadIdx.x & 31;
  const int ty = threadIdx.x >> 5;
  const int c0 = blockIdx.x * 32;
  const int r0 = blockIdx.y * 32;
#pragma unroll
  for (int i = 0; i < 4; i++) {
    int r = r0 + ty + i * 8;
    tile[ty + i * 8][tx] = quant_e4m3(in[(size_t)r * C + c0 + tx]);
  }
  __syncthreads();
  // tile[m_local][k_local]; emit k-pairs, coalesced along m (= tx)
#pragma unroll
  for (int i = 0; i < 2; i++) {
    int tl = ty + i * 8;                   // k-pair index 0..15
    u32 lo = (u32)__half_as_ushort(__float2half(tile[tx][2 * tl]));
    u32 hi = (u32)__half_as_ushort(__float2half(tile[tx][2 * tl + 1]));
    outp[(size_t)(c0 / 2 + tl) * R + r0 + tx] = lo | (hi << 16);
  }
}

// ---------- GEMM ----------

__device__ __forceinline__ void gld16(const void* g, void* l) {
  __builtin_amdgcn_global_load_lds((const __attribute__((address_space(1))) u32*)g,
                                   (__attribute__((address_space(3))) u32*)l, 16, 0, 0);
}

// acc = pk_fma(splat(x.lo), w, acc)  -- k0 of the packed pair
__device__ __forceinline__ void pkfma_lo(u32& acc, u32 x, u32 w) {
  asm("v_pk_fma_f16 %0, %1, %2, %0 op_sel:[0,0,0] op_sel_hi:[0,1,1]"
      : "+v"(acc) : "v"(x), "v"(w));
}
// acc = pk_fma(splat(x.hi), w, acc)  -- k1 of the packed pair
__device__ __forceinline__ void pkfma_hi(u32& acc, u32 x, u32 w) {
  asm("v_pk_fma_f16 %0, %1, %2, %0 op_sel:[1,0,0] op_sel_hi:[1,1,1]"
      : "+v"(acc) : "v"(x), "v"(w));
}

// xP [K/2][M] uints ({k0,k1} packed), wT [K][N] fp16, b [N] raw fp32,
// out [M][N] fp32.  Block: 128 threads, tile 32(m) x 128(n), thread 8x4.
__global__ __launch_bounds__(128) void gemm_qfma(const u32* __restrict__ xP,
                                                 const __half* __restrict__ wT,
                                                 const float* __restrict__ b,
                                                 float* __restrict__ outp) {
  __shared__ __align__(16) u32 xs[2][BK / 2][BM];     // 2 x 32 x 32 u32 =  8 KB
  __shared__ __align__(16) __half wsh[2][BK][BN];     // 2 x 64 x 128 h  = 32 KB
  const int tid = threadIdx.x;
  const int tn = tid & 31;    // 32 n-threads * 4 = BN
  const int tm = tid >> 5;    //  4 m-threads * 8 = BM
  const int bn0 = blockIdx.x * BN;
  const int bm0 = blockIdx.y * BM;
  const int xoff = tm << 3;   // uint col base in xs row
  const int woff = tn << 2;   // half col base in w row

  u32 acc[8][2];
#pragma unroll
  for (int i = 0; i < 8; i++) { acc[i][0] = 0u; acc[i][1] = 0u; }

  // staging source addresses (linear-LDS order == lane order, required by
  // global_load_lds wave-uniform-base + lane*16 semantics)
  const __half* wsrc = wT + (size_t)(tid >> 4) * N_DIM + bn0 + ((tid & 15) << 3);
  const u32*   xsrc = xP + (size_t)(tid >> 3) * M_DIM + bm0 + ((tid & 7) << 2);

  auto stage = [&](int ch, int buf) {
    const __half* wp = wsrc + (size_t)ch * BK * N_DIM;
    char* wl = (char*)&wsh[buf][0][0] + tid * 16;
#pragma unroll
    for (int j = 0; j < 8; j++)                       // 64 x 128 halfs, 16 KB
      gld16(wp + (size_t)(j * 8) * N_DIM, wl + j * 2048);
    const u32* xp = xsrc + (size_t)ch * (BK / 2) * M_DIM;
    char* xl = (char*)&xs[buf][0][0] + tid * 16;
#pragma unroll
    for (int j = 0; j < 2; j++)                       // 32 x 32 uints, 4 KB
      gld16(xp + (size_t)(j * 16) * M_DIM, xl + j * 2048);
  };

  auto compute = [&](int buf) {
#pragma unroll
    for (int tp = 0; tp < BK / 2; tp++) {             // k-pair: k0=2tp, k1=2tp+1
      u32 xv[8];
      *reinterpret_cast<uint4*>(&xv[0]) =
          *reinterpret_cast<const uint4*>(&xs[buf][tp][xoff]);
      *reinterpret_cast<uint4*>(&xv[4]) =
          *reinterpret_cast<const uint4*>(&xs[buf][tp][xoff + 4]);
      const uint2 w0 = *reinterpret_cast<const uint2*>(&wsh[buf][2 * tp][woff]);
      const uint2 w1 = *reinterpret_cast<const uint2*>(&wsh[buf][2 * tp + 1][woff]);
      // strict k order per accumulator: all k0 updates, then all k1 updates
#pragma unroll
      for (int i = 0; i < 8; i++) {
        pkfma_lo(acc[i][0], xv[i], w0.x);
        pkfma_lo(acc[i][1], xv[i], w0.y);
      }
#pragma unroll
      for (int i = 0; i < 8; i++) {
        pkfma_hi(acc[i][0], xv[i], w1.x);
        pkfma_hi(acc[i][1], xv[i], w1.y);
      }
    }
  };

  stage(0, 0);
  __syncthreads();
#pragma unroll 1
  for (int ch = 0; ch < NCHUNK; ch += 2) {
    stage(ch + 1, 1);          // issue-before-compute: latency hides under fmas
    compute(0);
    __syncthreads();           // implicit vmcnt(0)+lgkmcnt(0) drain
    if (ch + 2 < NCHUNK) stage(ch + 2, 0);
    compute(1);
    __syncthreads();
  }

  // epilogue: out = fp16RNE(acc + q8(b)), stored fp32 (fp32 add exact here)
  float4 bq;
  bq.x = quant_e4m3(b[bn0 + woff + 0]);
  bq.y = quant_e4m3(b[bn0 + woff + 1]);
  bq.z = quant_e4m3(b[bn0 + woff + 2]);
  bq.w = quant_e4m3(b[bn0 + woff + 3]);
#pragma unroll
  for (int i = 0; i < 8; i++) {
    __half2 a0 = *reinterpret_cast<__half2*>(&acc[i][0]);
    __half2 a1 = *reinterpret_cast<__half2*>(&acc[i][1]);
    float4 o;
    o.x = __half2float(__float2half(__low2float(a0)  + bq.x));
    o.y = __half2float(__float2half(__high2float(a0) + bq.y));
    o.z = __half2float(__float2half(__low2float(a1)  + bq.z));
    o.w = __half2float(__float2half(__high2float(a1) + bq.w));
    *reinterpret_cast<float4*>(outp + (size_t)(bm0 + xoff + i) * N_DIM + bn0 + woff) = o;
  }
}

extern "C" void kernel_launch(void* const* d_in, const int* in_sizes, int n_in,
                              void* d_out, int out_size, void* d_ws, size_t ws_size,
                              hipStream_t stream) {
  const float* x = (const float*)d_in[0];   // [2048][1024]
  const float* w = (const float*)d_in[1];   // [1024][1024] (out_f, in_f)
  const float* b = (const float*)d_in[2];   // [1024]
  float* outp = (float*)d_out;              // [2048][1024] fp32

  char* ws = (char*)d_ws;
  u32*    xP = (u32*)ws;                           // [K/2][M] uints, 4 MiB
  __half* wT = (__half*)(ws + (size_t)(4 << 20));  // [K][N] fp16,    2 MiB

  hipLaunchKernelGGL(qt_pack_kernel, dim3(K_DIM / 32, M_DIM / 32), dim3(256), 0, stream,
                     x, xP, M_DIM, K_DIM);
  hipLaunchKernelGGL(qt_kernel, dim3(K_DIM / 32, N_DIM / 32), dim3(256), 0, stream,
                     w, wT, N_DIM, K_DIM);
  hipLaunchKernelGGL(gemm_qfma, dim3(N_DIM / BN, M_DIM / BM), dim3(128), 0, stream,
                     xP, wT, b, outp);
}